// Round 4
// baseline (193.745 us; speedup 1.0000x reference)
//
#include <hip/hip_runtime.h>
#include <hip/hip_bf16.h>

// S4 layer: y = irfft( rfft(pad(u)) * (rfft(pad(K)) + D) )[:L]
// B=16, H=128, L=4096, N=64. All fp32.
// FFT4096 = 16^3 register FFT: 3x in-register FFT16 + 2 LDS transposes.
// Spectral step uses precomputed per-bin alpha/beta (built in k_khat):
//   Ypack[k] = alpha[h,k]*Z[k] + beta[h,k]*conj(Z[(4096-k)&4095])
// k_conv uses an XOR-swizzled zero-pad LDS layout: exactly 4096 float2
// = 32.0 KB -> 5 blocks/CU (pad-17 was 34.9 KB -> 4 blocks/CU). Bank
// profile identical (16 distinct bank-pairs per wave op in all stages).
// k_khat (128 blocks, latency-irrelevant) keeps the pad-17 path.
// ws: [0,4MiB) atR 128x4096 float2 ; [4MiB,12MiB) abt 128x4096 float4 (scrambled)

#define PI_F 3.14159265358979323846f

__device__ __forceinline__ float2 cmulf(float2 a, float2 b) {
  return make_float2(a.x * b.x - a.y * b.y, a.x * b.y + a.y * b.x);
}
__device__ __forceinline__ void cmul_set(float2& v, float wr, float wi) {
  v = make_float2(v.x * wr - v.y * wi, v.x * wi + v.y * wr);
}
__device__ __forceinline__ int ad(int k) { return k + (k >> 4); }   // pad-17
__device__ __forceinline__ int sw16(int j) { return j ^ ((j >> 4) & 15); }

template <int SIGN>
__device__ __forceinline__ void bfly4(float2& a, float2& b, float2& c,
                                      float2& d) {
  float t0x = a.x + c.x, t0y = a.y + c.y;
  float t1x = a.x - c.x, t1y = a.y - c.y;
  float t2x = b.x + d.x, t2y = b.y + d.y;
  float t3x = b.x - d.x, t3y = b.y - d.y;
  a = make_float2(t0x + t2x, t0y + t2y);
  c = make_float2(t0x - t2x, t0y - t2y);
  if (SIGN < 0) {
    b = make_float2(t1x + t3y, t1y - t3x);
    d = make_float2(t1x - t3y, t1y + t3x);
  } else {
    b = make_float2(t1x - t3y, t1y + t3x);
    d = make_float2(t1x + t3y, t1y - t3x);
  }
}

// in-register 16-point DFT, natural in / natural out, constant twiddles.
template <int SIGN>
__device__ __forceinline__ void fft16(float2 v[16]) {
  const float sg = (float)SIGN;
  const float C1 = 0.92387953251128674f;
  const float S1 = 0.38268343236508978f;
  const float R2 = 0.70710678118654752f;
  bfly4<SIGN>(v[0], v[4], v[8], v[12]);
  bfly4<SIGN>(v[1], v[5], v[9], v[13]);
  bfly4<SIGN>(v[2], v[6], v[10], v[14]);
  bfly4<SIGN>(v[3], v[7], v[11], v[15]);
  cmul_set(v[5], C1, sg * S1);
  cmul_set(v[6], R2, sg * R2);
  cmul_set(v[7], S1, sg * C1);
  cmul_set(v[9], R2, sg * R2);
  v[10] = make_float2(-sg * v[10].y, sg * v[10].x);
  cmul_set(v[11], -R2, sg * R2);
  cmul_set(v[13], S1, sg * C1);
  cmul_set(v[14], -R2, sg * R2);
  cmul_set(v[15], -C1, -sg * S1);
  float2 w[16];
#pragma unroll
  for (int g = 0; g < 4; ++g) {
    float2 x0 = v[4 * g], x1 = v[4 * g + 1], x2 = v[4 * g + 2],
           x3 = v[4 * g + 3];
    bfly4<SIGN>(x0, x1, x2, x3);
    w[g] = x0; w[g + 4] = x1; w[g + 8] = x2; w[g + 12] = x3;
  }
#pragma unroll
  for (int i = 0; i < 16; ++i) v[i] = w[i];
}

__device__ __forceinline__ void tw_apply(float2 v[16], float ang) {
  float sn, cn;
  __sincosf(ang, &sn, &cn);
  float2 w1 = make_float2(cn, sn), cw = w1;
#pragma unroll
  for (int g = 1; g < 16; ++g) {
    v[g] = cmulf(v[g], cw);
    if (g < 15) cw = cmulf(cw, w1);
  }
}

// ======== pad-17 variant (k_khat only; lds is 4368 float2) ========
// natural -> scrambled. In: v[c] = x[tid+256c].
// Out: v[al] = X[kb + 256*al], kb = (tid>>4) + 16*(tid&15).
template <int SIGN>
__device__ void fft4096_regs(float2 v[16], float2* lds, int tid) {
  const int a = tid & 15, g2 = tid >> 4;
  fft16<SIGN>(v);
  tw_apply(v, (float)SIGN * (2.0f * PI_F / 4096.0f) * (float)tid);
  __syncthreads();
#pragma unroll
  for (int g = 0; g < 16; ++g) lds[tid * 17 + g] = v[g];
  __syncthreads();
#pragma unroll
  for (int b = 0; b < 16; ++b) v[b] = lds[a * 17 + b * 272 + g2];
  fft16<SIGN>(v);
  tw_apply(v, (float)SIGN * (2.0f * PI_F / 256.0f) * (float)a);
  __syncthreads();
#pragma unroll
  for (int b = 0; b < 16; ++b) lds[g2 * 17 + b * 273 + a] = v[b];
  __syncthreads();
#pragma unroll
  for (int a2 = 0; a2 < 16; ++a2) v[a2] = lds[g2 * 17 + a * 273 + a2];
  fft16<SIGN>(v);
  // no trailing barrier; callers must __syncthreads before reusing lds.
}

// ======== swizzled variant (k_conv; lds is exactly 4096 float2) ========
template <int SIGN>
__device__ void fft4096_regs_c(float2 v[16], float2* lds, int tid) {
  const int a = tid & 15, g2 = tid >> 4;
  fft16<SIGN>(v);
  tw_apply(v, (float)SIGN * (2.0f * PI_F / 4096.0f) * (float)tid);
  __syncthreads();
#pragma unroll
  for (int g = 0; g < 16; ++g) lds[(tid << 4) | (g ^ a)] = v[g];
  __syncthreads();
#pragma unroll
  for (int b = 0; b < 16; ++b) v[b] = lds[((a + 16 * b) << 4) | (g2 ^ a)];
  fft16<SIGN>(v);
  tw_apply(v, (float)SIGN * (2.0f * PI_F / 256.0f) * (float)a);
  __syncthreads();
#pragma unroll
  for (int b = 0; b < 16; ++b) lds[(g2 << 8) | (b << 4) | (a ^ b)] = v[b];
  __syncthreads();
#pragma unroll
  for (int a2 = 0; a2 < 16; ++a2) v[a2] = lds[(g2 << 8) | (a << 4) | (a2 ^ a)];
  fft16<SIGN>(v);
  // no trailing barrier.
}

// scrambled -> natural (reverse network), swizzled layout.
template <int SIGN>
__device__ void fft4096_scr2nat_c(float2 v[16], float2* lds, int tid) {
  const int a = tid & 15, g2 = tid >> 4;
  fft16<SIGN>(v);  // over k2
  __syncthreads();  // guard callers' prior lds reads
#pragma unroll
  for (int r = 0; r < 16; ++r) lds[(g2 << 8) | (a << 4) | (r ^ a)] = v[r];
  __syncthreads();
#pragma unroll
  for (int b = 0; b < 16; ++b) v[b] = lds[(g2 << 8) | (b << 4) | (a ^ b)];
  tw_apply(v, (float)SIGN * (2.0f * PI_F / 256.0f) * (float)a);
  fft16<SIGN>(v);  // over k1
  __syncthreads();
#pragma unroll
  for (int r = 0; r < 16; ++r) lds[((16 * r + a) << 4) | (g2 ^ a)] = v[r];
  __syncthreads();
#pragma unroll
  for (int g = 0; g < 16; ++g) v[g] = lds[(tid << 4) | (g ^ a)];
  tw_apply(v, (float)SIGN * (2.0f * PI_F / 4096.0f) * (float)tid);
  fft16<SIGN>(v);  // over k0 -> v[c] = x[tid+256c]
}

// ---------------- Kernel 1a: Cauchy sums -> atRoots ----------------
// 2048 blocks: h=blk>>4, 1 m-point/thread (8 waves/SIMD for latency hiding).
__global__ __launch_bounds__(256) void k_cauchy(
    const float* __restrict__ Lre, const float* __restrict__ Lim,
    const float* __restrict__ Pri, const float* __restrict__ Bri,
    const float* __restrict__ Cri, const float* __restrict__ lstep,
    float2* __restrict__ atR) {
  __shared__ float4 pA[64];
  __shared__ float4 pB[64];
  __shared__ float2 pL[64];
  const int h = blockIdx.x >> 4;
  const int sub = blockIdx.x & 15;
  const int tid = threadIdx.x;
  if (tid < 64) {
    int base = h * 64 + tid;
    float lr = fminf(Lre[base], -1e-4f);
    float li = Lim[base];
    float pr = Pri[2 * base], pi = Pri[2 * base + 1];
    float br = Bri[2 * base], bi = Bri[2 * base + 1];
    float cr = Cri[2 * base], ci = Cri[2 * base + 1];
    pA[tid] = make_float4(cr * br + ci * bi, cr * bi - ci * br,
                          cr * pr + ci * pi, cr * pi - ci * pr);
    pB[tid] = make_float4(pr * br + pi * bi, pr * bi - pi * br,
                          pr * pr + pi * pi, 0.f);
    pL[tid] = make_float2(lr, li);
  }
  __syncthreads();
  const float istep = expf(-lstep[h]);
  const int m = sub * 256 + tid;
  float sn, cn;
  __sincosf(-(2.0f * PI_F / 4096.0f) * (float)m, &sn, &cn);
  const float trm = 0.5f * (1.0f + cn);
  const float tim = 0.5f * sn;
  const float qrm = (1.0f - cn) * istep;
  const float qim = -sn * istep;
  float S0 = 0.f, S1 = 0.f, S2 = 0.f, S3 = 0.f, S4 = 0.f, S5 = 0.f, S6 = 0.f,
        S7 = 0.f;
#pragma unroll 8
  for (int n = 0; n < 64; ++n) {
    float4 a = pA[n];
    float4 b = pB[n];
    float2 L = pL[n];
    float dr = qrm - (trm * L.x - tim * L.y);
    float di = qim - (trm * L.y + tim * L.x);
    float inv = __builtin_amdgcn_rcpf(dr * dr + di * di);
    float sr = dr * inv, si = -di * inv;
    S0 += a.x * sr - a.y * si;  S1 += a.x * si + a.y * sr;
    S2 += a.z * sr - a.w * si;  S3 += a.z * si + a.w * sr;
    S4 += b.x * sr - b.y * si;  S5 += b.x * si + b.y * sr;
    S6 += b.z * sr;             S7 += b.z * si;
  }
  float tS11r = trm * S6 - tim * S7;
  float tS11i = trm * S7 + tim * S6;
  float denr = 1.0f + tS11r, deni = tS11i;
  float dinv = 1.0f / (denr * denr + deni * deni);
  float P1r = S2 * S4 - S3 * S5;
  float P1i = S2 * S5 + S3 * S4;
  float P2r = trm * P1r - tim * P1i;
  float P2i = trm * P1i + tim * P1r;
  float Qr = (P2r * denr + P2i * deni) * dinv;
  float Qi = (P2i * denr - P2r * deni) * dinv;
  atR[h * 4096 + m] = make_float2(S0 - Qr, S1 - Qi);
}

// ---------------- Kernel 1b: atRoots -> alpha/beta table ----------------
__global__ __launch_bounds__(256, 4) void k_khat(
    const float2* __restrict__ atR, const float* __restrict__ Dp,
    float4* __restrict__ abt) {
  __shared__ float2 lds[4368];
  const int h = blockIdx.x;
  const int tid = threadIdx.x;
  float2 v[16];
#pragma unroll
  for (int c = 0; c < 16; ++c) v[c] = atR[h * 4096 + tid + 256 * c];
  fft4096_regs<1>(v, lds, tid);  // unnormalized inverse -> zK (scrambled)
  const int kb = (tid >> 4) + 16 * (tid & 15);
  float* ldsf = (float*)lds;
  const float s = 1.0f / 4096.0f;
  __syncthreads();
#pragma unroll
  for (int al = 0; al < 16; ++al) ldsf[ad(kb + 256 * al)] = v[al].x * s;
  __syncthreads();
  // pack K[2n]+iK[2n+1], zero-pad to 2L
#pragma unroll
  for (int c = 0; c < 8; ++c) {
    int n = tid + 256 * c;
    v[c] = make_float2(ldsf[ad(2 * n)], ldsf[ad(2 * n + 1)]);
  }
#pragma unroll
  for (int c = 8; c < 16; ++c) v[c] = make_float2(0.f, 0.f);
  fft4096_regs<-1>(v, lds, tid);  // forward; scrambled
  __syncthreads();
#pragma unroll
  for (int al = 0; al < 16; ++al) lds[ad(kb + 256 * al)] = v[al];
  __syncthreads();
  const float Dh = Dp[h];
#pragma unroll
  for (int c = 0; c < 16; ++c) {
    int k = kb + 256 * c;
    float2 Zk = lds[ad(k)];
    float2 Zm = lds[ad((4096 - k) & 4095)];
    float Er = 0.5f * (Zk.x + Zm.x), Ei = 0.5f * (Zk.y - Zm.y);
    float Or = 0.5f * (Zk.y + Zm.y), Oi = 0.5f * (Zm.x - Zk.x);
    float s_, c_;
    __sincosf(-(PI_F / 4096.0f) * (float)k, &s_, &c_);
    float Gr = c_ * Or - s_ * Oi, Gi = c_ * Oi + s_ * Or;  // G = W*O
    float ar = (Er + Dh + s_ * Gr) * s;
    float ai = (Ei + s_ * Gi) * s;
    float br = (-c_ * Gi) * s;
    float bi = (c_ * Gr) * s;
    abt[h * 4096 + tid + 256 * c] = make_float4(ar, ai, br, bi);  // scrambled
  }
}

// ---------------- Kernel 2: per-row FFT convolution ----------------
__global__ __launch_bounds__(256, 5) void k_conv(const float* __restrict__ u,
                                                 const float4* __restrict__ abt,
                                                 float* __restrict__ y) {
  __shared__ float2 lds[4096];  // exactly 32 KB -> 5 blocks/CU
  const int r = blockIdx.x;  // b*128 + h
  const int h = r & 127;
  const int tid = threadIdx.x;
  const float2* u2 = (const float2*)(u + (size_t)r * 4096);
  float2 v[16];
#pragma unroll
  for (int c = 0; c < 8; ++c) v[c] = u2[tid + 256 * c];
#pragma unroll
  for (int c = 8; c < 16; ++c) v[c] = make_float2(0.f, 0.f);
  fft4096_regs_c<-1>(v, lds, tid);  // forward; v[al]=Z[kb+256al]
  const int kb = (tid >> 4) + 16 * (tid & 15);
  __syncthreads();  // lagging T2 reads done before we overwrite
#pragma unroll
  for (int al = 0; al < 16; ++al) lds[sw16(kb + 256 * al)] = v[al];
  __syncthreads();
  const float4* __restrict__ abrow = abt + h * 4096;
#pragma unroll
  for (int al = 0; al < 16; ++al) {
    int k = kb + 256 * al;
    float4 ab = abrow[tid + 256 * al];  // coalesced (pre-scrambled table)
    float2 Zm = lds[sw16((4096 - k) & 4095)];
    float2 Zk = v[al];
    v[al] = make_float2(ab.x * Zk.x - ab.y * Zk.y + ab.z * Zm.x + ab.w * Zm.y,
                        ab.x * Zk.y + ab.y * Zk.x + ab.w * Zm.x - ab.z * Zm.y);
  }
  // inverse from scrambled; internal first sync guards partner reads above
  fft4096_scr2nat_c<1>(v, lds, tid);  // v[c] = ypack[tid+256c]
  float2* y2 = (float2*)(y + (size_t)r * 4096);
#pragma unroll
  for (int c = 0; c < 8; ++c) y2[tid + 256 * c] = v[c];
}

extern "C" void kernel_launch(void* const* d_in, const int* in_sizes, int n_in,
                              void* d_out, int out_size, void* d_ws,
                              size_t ws_size, hipStream_t stream) {
  (void)in_sizes; (void)n_in; (void)out_size; (void)ws_size;
  const float* u = (const float*)d_in[0];
  const float* Lre = (const float*)d_in[1];
  const float* Lim = (const float*)d_in[2];
  const float* Pri = (const float*)d_in[3];
  const float* Bri = (const float*)d_in[4];
  const float* Cri = (const float*)d_in[5];
  const float* lst = (const float*)d_in[6];
  const float* Dp = (const float*)d_in[7];
  float* y = (float*)d_out;
  float2* atR = (float2*)d_ws;                                     // 4 MiB
  float4* abt = (float4*)((char*)d_ws + (size_t)4 * 1024 * 1024);  // 8 MiB

  k_cauchy<<<2048, 256, 0, stream>>>(Lre, Lim, Pri, Bri, Cri, lst, atR);
  k_khat<<<128, 256, 0, stream>>>(atR, Dp, abt);
  k_conv<<<2048, 256, 0, stream>>>(u, abt, y);
}

// Round 5
// 164.676 us; speedup vs baseline: 1.1765x; 1.1765x over previous
//
#include <hip/hip_runtime.h>
#include <hip/hip_bf16.h>

// S4 layer: y = irfft( rfft(pad(u)) * (rfft(pad(K)) + D) )[:L]
// B=16, H=128, L=4096, N=64. All fp32.
// FFT4096 = 16^3 register FFT: 3x in-register FFT16 + 2 LDS transposes.
// Spectral step uses precomputed per-bin alpha/beta (built in k_khat):
//   Ypack[k] = alpha[h,k]*Z[k] + beta[h,k]*conj(Z[(4096-k)&4095])
// k_conv uses an XOR-swizzled LDS layout: exactly 4096 float2 = 32.0 KB
// -> LDS-bound occupancy 5 blocks/CU. launch_bounds kept at (256,4): R4
// showed (256,5) forces VGPR 64->48 and spills v[16] to scratch
// (FETCH 20->89MB, WRITE 33->139MB). (256,4) compiles to 64 VGPR, no
// spill; HW occupancy = min(LDS:5, VGPR:8) = 5 blocks/CU anyway.
// ws: [0,4MiB) atR 128x4096 float2 ; [4MiB,12MiB) abt 128x4096 float4 (scrambled)

#define PI_F 3.14159265358979323846f

__device__ __forceinline__ float2 cmulf(float2 a, float2 b) {
  return make_float2(a.x * b.x - a.y * b.y, a.x * b.y + a.y * b.x);
}
__device__ __forceinline__ void cmul_set(float2& v, float wr, float wi) {
  v = make_float2(v.x * wr - v.y * wi, v.x * wi + v.y * wr);
}
__device__ __forceinline__ int ad(int k) { return k + (k >> 4); }   // pad-17
__device__ __forceinline__ int sw16(int j) { return j ^ ((j >> 4) & 15); }

template <int SIGN>
__device__ __forceinline__ void bfly4(float2& a, float2& b, float2& c,
                                      float2& d) {
  float t0x = a.x + c.x, t0y = a.y + c.y;
  float t1x = a.x - c.x, t1y = a.y - c.y;
  float t2x = b.x + d.x, t2y = b.y + d.y;
  float t3x = b.x - d.x, t3y = b.y - d.y;
  a = make_float2(t0x + t2x, t0y + t2y);
  c = make_float2(t0x - t2x, t0y - t2y);
  if (SIGN < 0) {
    b = make_float2(t1x + t3y, t1y - t3x);
    d = make_float2(t1x - t3y, t1y + t3x);
  } else {
    b = make_float2(t1x - t3y, t1y + t3x);
    d = make_float2(t1x + t3y, t1y - t3x);
  }
}

// in-register 16-point DFT, natural in / natural out, constant twiddles.
template <int SIGN>
__device__ __forceinline__ void fft16(float2 v[16]) {
  const float sg = (float)SIGN;
  const float C1 = 0.92387953251128674f;
  const float S1 = 0.38268343236508978f;
  const float R2 = 0.70710678118654752f;
  bfly4<SIGN>(v[0], v[4], v[8], v[12]);
  bfly4<SIGN>(v[1], v[5], v[9], v[13]);
  bfly4<SIGN>(v[2], v[6], v[10], v[14]);
  bfly4<SIGN>(v[3], v[7], v[11], v[15]);
  cmul_set(v[5], C1, sg * S1);
  cmul_set(v[6], R2, sg * R2);
  cmul_set(v[7], S1, sg * C1);
  cmul_set(v[9], R2, sg * R2);
  v[10] = make_float2(-sg * v[10].y, sg * v[10].x);
  cmul_set(v[11], -R2, sg * R2);
  cmul_set(v[13], S1, sg * C1);
  cmul_set(v[14], -R2, sg * R2);
  cmul_set(v[15], -C1, -sg * S1);
  float2 w[16];
#pragma unroll
  for (int g = 0; g < 4; ++g) {
    float2 x0 = v[4 * g], x1 = v[4 * g + 1], x2 = v[4 * g + 2],
           x3 = v[4 * g + 3];
    bfly4<SIGN>(x0, x1, x2, x3);
    w[g] = x0; w[g + 4] = x1; w[g + 8] = x2; w[g + 12] = x3;
  }
#pragma unroll
  for (int i = 0; i < 16; ++i) v[i] = w[i];
}

__device__ __forceinline__ void tw_apply(float2 v[16], float ang) {
  float sn, cn;
  __sincosf(ang, &sn, &cn);
  float2 w1 = make_float2(cn, sn), cw = w1;
#pragma unroll
  for (int g = 1; g < 16; ++g) {
    v[g] = cmulf(v[g], cw);
    if (g < 15) cw = cmulf(cw, w1);
  }
}

// ======== pad-17 variant (k_khat only; lds is 4368 float2) ========
// natural -> scrambled. In: v[c] = x[tid+256c].
// Out: v[al] = X[kb + 256*al], kb = (tid>>4) + 16*(tid&15).
template <int SIGN>
__device__ void fft4096_regs(float2 v[16], float2* lds, int tid) {
  const int a = tid & 15, g2 = tid >> 4;
  fft16<SIGN>(v);
  tw_apply(v, (float)SIGN * (2.0f * PI_F / 4096.0f) * (float)tid);
  __syncthreads();
#pragma unroll
  for (int g = 0; g < 16; ++g) lds[tid * 17 + g] = v[g];
  __syncthreads();
#pragma unroll
  for (int b = 0; b < 16; ++b) v[b] = lds[a * 17 + b * 272 + g2];
  fft16<SIGN>(v);
  tw_apply(v, (float)SIGN * (2.0f * PI_F / 256.0f) * (float)a);
  __syncthreads();
#pragma unroll
  for (int b = 0; b < 16; ++b) lds[g2 * 17 + b * 273 + a] = v[b];
  __syncthreads();
#pragma unroll
  for (int a2 = 0; a2 < 16; ++a2) v[a2] = lds[g2 * 17 + a * 273 + a2];
  fft16<SIGN>(v);
  // no trailing barrier; callers must __syncthreads before reusing lds.
}

// ======== swizzled variant (k_conv; lds is exactly 4096 float2) ========
template <int SIGN>
__device__ void fft4096_regs_c(float2 v[16], float2* lds, int tid) {
  const int a = tid & 15, g2 = tid >> 4;
  fft16<SIGN>(v);
  tw_apply(v, (float)SIGN * (2.0f * PI_F / 4096.0f) * (float)tid);
  __syncthreads();
#pragma unroll
  for (int g = 0; g < 16; ++g) lds[(tid << 4) | (g ^ a)] = v[g];
  __syncthreads();
#pragma unroll
  for (int b = 0; b < 16; ++b) v[b] = lds[((a + 16 * b) << 4) | (g2 ^ a)];
  fft16<SIGN>(v);
  tw_apply(v, (float)SIGN * (2.0f * PI_F / 256.0f) * (float)a);
  __syncthreads();
#pragma unroll
  for (int b = 0; b < 16; ++b) lds[(g2 << 8) | (b << 4) | (a ^ b)] = v[b];
  __syncthreads();
#pragma unroll
  for (int a2 = 0; a2 < 16; ++a2) v[a2] = lds[(g2 << 8) | (a << 4) | (a2 ^ a)];
  fft16<SIGN>(v);
  // no trailing barrier.
}

// scrambled -> natural (reverse network), swizzled layout.
template <int SIGN>
__device__ void fft4096_scr2nat_c(float2 v[16], float2* lds, int tid) {
  const int a = tid & 15, g2 = tid >> 4;
  fft16<SIGN>(v);  // over k2
  __syncthreads();  // guard callers' prior lds reads
#pragma unroll
  for (int r = 0; r < 16; ++r) lds[(g2 << 8) | (a << 4) | (r ^ a)] = v[r];
  __syncthreads();
#pragma unroll
  for (int b = 0; b < 16; ++b) v[b] = lds[(g2 << 8) | (b << 4) | (a ^ b)];
  tw_apply(v, (float)SIGN * (2.0f * PI_F / 256.0f) * (float)a);
  fft16<SIGN>(v);  // over k1
  __syncthreads();
#pragma unroll
  for (int r = 0; r < 16; ++r) lds[((16 * r + a) << 4) | (g2 ^ a)] = v[r];
  __syncthreads();
#pragma unroll
  for (int g = 0; g < 16; ++g) v[g] = lds[(tid << 4) | (g ^ a)];
  tw_apply(v, (float)SIGN * (2.0f * PI_F / 4096.0f) * (float)tid);
  fft16<SIGN>(v);  // over k0 -> v[c] = x[tid+256c]
}

// ---------------- Kernel 1a: Cauchy sums -> atRoots ----------------
// 2048 blocks: h=blk>>4, 1 m-point/thread (8 waves/SIMD for latency hiding).
__global__ __launch_bounds__(256) void k_cauchy(
    const float* __restrict__ Lre, const float* __restrict__ Lim,
    const float* __restrict__ Pri, const float* __restrict__ Bri,
    const float* __restrict__ Cri, const float* __restrict__ lstep,
    float2* __restrict__ atR) {
  __shared__ float4 pA[64];
  __shared__ float4 pB[64];
  __shared__ float2 pL[64];
  const int h = blockIdx.x >> 4;
  const int sub = blockIdx.x & 15;
  const int tid = threadIdx.x;
  if (tid < 64) {
    int base = h * 64 + tid;
    float lr = fminf(Lre[base], -1e-4f);
    float li = Lim[base];
    float pr = Pri[2 * base], pi = Pri[2 * base + 1];
    float br = Bri[2 * base], bi = Bri[2 * base + 1];
    float cr = Cri[2 * base], ci = Cri[2 * base + 1];
    pA[tid] = make_float4(cr * br + ci * bi, cr * bi - ci * br,
                          cr * pr + ci * pi, cr * pi - ci * pr);
    pB[tid] = make_float4(pr * br + pi * bi, pr * bi - pi * br,
                          pr * pr + pi * pi, 0.f);
    pL[tid] = make_float2(lr, li);
  }
  __syncthreads();
  const float istep = expf(-lstep[h]);
  const int m = sub * 256 + tid;
  float sn, cn;
  __sincosf(-(2.0f * PI_F / 4096.0f) * (float)m, &sn, &cn);
  const float trm = 0.5f * (1.0f + cn);
  const float tim = 0.5f * sn;
  const float qrm = (1.0f - cn) * istep;
  const float qim = -sn * istep;
  float S0 = 0.f, S1 = 0.f, S2 = 0.f, S3 = 0.f, S4 = 0.f, S5 = 0.f, S6 = 0.f,
        S7 = 0.f;
#pragma unroll 8
  for (int n = 0; n < 64; ++n) {
    float4 a = pA[n];
    float4 b = pB[n];
    float2 L = pL[n];
    float dr = qrm - (trm * L.x - tim * L.y);
    float di = qim - (trm * L.y + tim * L.x);
    float inv = __builtin_amdgcn_rcpf(dr * dr + di * di);
    float sr = dr * inv, si = -di * inv;
    S0 += a.x * sr - a.y * si;  S1 += a.x * si + a.y * sr;
    S2 += a.z * sr - a.w * si;  S3 += a.z * si + a.w * sr;
    S4 += b.x * sr - b.y * si;  S5 += b.x * si + b.y * sr;
    S6 += b.z * sr;             S7 += b.z * si;
  }
  float tS11r = trm * S6 - tim * S7;
  float tS11i = trm * S7 + tim * S6;
  float denr = 1.0f + tS11r, deni = tS11i;
  float dinv = 1.0f / (denr * denr + deni * deni);
  float P1r = S2 * S4 - S3 * S5;
  float P1i = S2 * S5 + S3 * S4;
  float P2r = trm * P1r - tim * P1i;
  float P2i = trm * P1i + tim * P1r;
  float Qr = (P2r * denr + P2i * deni) * dinv;
  float Qi = (P2i * denr - P2r * deni) * dinv;
  atR[h * 4096 + m] = make_float2(S0 - Qr, S1 - Qi);
}

// ---------------- Kernel 1b: atRoots -> alpha/beta table ----------------
__global__ __launch_bounds__(256, 4) void k_khat(
    const float2* __restrict__ atR, const float* __restrict__ Dp,
    float4* __restrict__ abt) {
  __shared__ float2 lds[4368];
  const int h = blockIdx.x;
  const int tid = threadIdx.x;
  float2 v[16];
#pragma unroll
  for (int c = 0; c < 16; ++c) v[c] = atR[h * 4096 + tid + 256 * c];
  fft4096_regs<1>(v, lds, tid);  // unnormalized inverse -> zK (scrambled)
  const int kb = (tid >> 4) + 16 * (tid & 15);
  float* ldsf = (float*)lds;
  const float s = 1.0f / 4096.0f;
  __syncthreads();
#pragma unroll
  for (int al = 0; al < 16; ++al) ldsf[ad(kb + 256 * al)] = v[al].x * s;
  __syncthreads();
  // pack K[2n]+iK[2n+1], zero-pad to 2L
#pragma unroll
  for (int c = 0; c < 8; ++c) {
    int n = tid + 256 * c;
    v[c] = make_float2(ldsf[ad(2 * n)], ldsf[ad(2 * n + 1)]);
  }
#pragma unroll
  for (int c = 8; c < 16; ++c) v[c] = make_float2(0.f, 0.f);
  fft4096_regs<-1>(v, lds, tid);  // forward; scrambled
  __syncthreads();
#pragma unroll
  for (int al = 0; al < 16; ++al) lds[ad(kb + 256 * al)] = v[al];
  __syncthreads();
  const float Dh = Dp[h];
#pragma unroll
  for (int c = 0; c < 16; ++c) {
    int k = kb + 256 * c;
    float2 Zk = lds[ad(k)];
    float2 Zm = lds[ad((4096 - k) & 4095)];
    float Er = 0.5f * (Zk.x + Zm.x), Ei = 0.5f * (Zk.y - Zm.y);
    float Or = 0.5f * (Zk.y + Zm.y), Oi = 0.5f * (Zm.x - Zk.x);
    float s_, c_;
    __sincosf(-(PI_F / 4096.0f) * (float)k, &s_, &c_);
    float Gr = c_ * Or - s_ * Oi, Gi = c_ * Oi + s_ * Or;  // G = W*O
    float ar = (Er + Dh + s_ * Gr) * s;
    float ai = (Ei + s_ * Gi) * s;
    float br = (-c_ * Gi) * s;
    float bi = (c_ * Gr) * s;
    abt[h * 4096 + tid + 256 * c] = make_float4(ar, ai, br, bi);  // scrambled
  }
}

// ---------------- Kernel 2: per-row FFT convolution ----------------
// (256,4): R3-proven 64 VGPR / no spill. Do NOT raise to (256,5) — R4
// showed it forces 48 VGPR and spills ~200MB of scratch per dispatch.
__global__ __launch_bounds__(256, 4) void k_conv(const float* __restrict__ u,
                                                 const float4* __restrict__ abt,
                                                 float* __restrict__ y) {
  __shared__ float2 lds[4096];  // exactly 32 KB -> LDS cap 5 blocks/CU
  const int r = blockIdx.x;  // b*128 + h
  const int h = r & 127;
  const int tid = threadIdx.x;
  const float2* u2 = (const float2*)(u + (size_t)r * 4096);
  float2 v[16];
#pragma unroll
  for (int c = 0; c < 8; ++c) v[c] = u2[tid + 256 * c];
#pragma unroll
  for (int c = 8; c < 16; ++c) v[c] = make_float2(0.f, 0.f);
  fft4096_regs_c<-1>(v, lds, tid);  // forward; v[al]=Z[kb+256al]
  const int kb = (tid >> 4) + 16 * (tid & 15);
  __syncthreads();  // lagging T2 reads done before we overwrite
#pragma unroll
  for (int al = 0; al < 16; ++al) lds[sw16(kb + 256 * al)] = v[al];
  __syncthreads();
  const float4* __restrict__ abrow = abt + h * 4096;
#pragma unroll
  for (int al = 0; al < 16; ++al) {
    int k = kb + 256 * al;
    float4 ab = abrow[tid + 256 * al];  // coalesced (pre-scrambled table)
    float2 Zm = lds[sw16((4096 - k) & 4095)];
    float2 Zk = v[al];
    v[al] = make_float2(ab.x * Zk.x - ab.y * Zk.y + ab.z * Zm.x + ab.w * Zm.y,
                        ab.x * Zk.y + ab.y * Zk.x + ab.w * Zm.x - ab.z * Zm.y);
  }
  // inverse from scrambled; internal first sync guards partner reads above
  fft4096_scr2nat_c<1>(v, lds, tid);  // v[c] = ypack[tid+256c]
  float2* y2 = (float2*)(y + (size_t)r * 4096);
#pragma unroll
  for (int c = 0; c < 8; ++c) y2[tid + 256 * c] = v[c];
}

extern "C" void kernel_launch(void* const* d_in, const int* in_sizes, int n_in,
                              void* d_out, int out_size, void* d_ws,
                              size_t ws_size, hipStream_t stream) {
  (void)in_sizes; (void)n_in; (void)out_size; (void)ws_size;
  const float* u = (const float*)d_in[0];
  const float* Lre = (const float*)d_in[1];
  const float* Lim = (const float*)d_in[2];
  const float* Pri = (const float*)d_in[3];
  const float* Bri = (const float*)d_in[4];
  const float* Cri = (const float*)d_in[5];
  const float* lst = (const float*)d_in[6];
  const float* Dp = (const float*)d_in[7];
  float* y = (float*)d_out;
  float2* atR = (float2*)d_ws;                                     // 4 MiB
  float4* abt = (float4*)((char*)d_ws + (size_t)4 * 1024 * 1024);  // 8 MiB

  k_cauchy<<<2048, 256, 0, stream>>>(Lre, Lim, Pri, Bri, Cri, lst, atR);
  k_khat<<<128, 256, 0, stream>>>(atR, Dp, abt);
  k_conv<<<2048, 256, 0, stream>>>(u, abt, y);
}

// Round 6
// 157.501 us; speedup vs baseline: 1.2301x; 1.0456x over previous
//
#include <hip/hip_runtime.h>
#include <hip/hip_bf16.h>

// S4 layer: y = irfft( rfft(pad(u)) * (rfft(pad(K)) + D) )[:L]
// B=16, H=128, L=4096, N=64. All fp32.
// FFT4096 = 16^3 register FFT: 3x in-register FFT16 + 2 LDS transposes.
// Spectral step uses precomputed per-bin alpha/beta (built in k_khat):
//   Ypack[k] = alpha[h,k]*Z[k] + beta[h,k]*conj(Z[(4096-k)&4095])
// k_conv: XOR-swizzled LDS layout, exactly 4096 float2 = 32.0 KB ->
// LDS-bound occupancy 5 blocks/CU.
// launch_bounds history (do not regress):
//   (256,5): VGPR cap 48 -> massive spill (FETCH 89MB WRITE 139MB), 76us.
//   (256,4): VGPR cap 64 -> swizzle variant spills ~13 dw/thread
//            (WRITE 33->59MB), 46us. pad-17 fits in 64 exactly.
//   (256,2): VGPR cap 128 -> swizzle fits (~77 natural), no spill;
//            occupancy still LDS-capped at 5 blocks/CU.
// ws: [0,4MiB) atR 128x4096 float2 ; [4MiB,12MiB) abt 128x4096 float4 (scrambled)

#define PI_F 3.14159265358979323846f

__device__ __forceinline__ float2 cmulf(float2 a, float2 b) {
  return make_float2(a.x * b.x - a.y * b.y, a.x * b.y + a.y * b.x);
}
__device__ __forceinline__ void cmul_set(float2& v, float wr, float wi) {
  v = make_float2(v.x * wr - v.y * wi, v.x * wi + v.y * wr);
}
__device__ __forceinline__ int ad(int k) { return k + (k >> 4); }   // pad-17
__device__ __forceinline__ int sw16(int j) { return j ^ ((j >> 4) & 15); }

template <int SIGN>
__device__ __forceinline__ void bfly4(float2& a, float2& b, float2& c,
                                      float2& d) {
  float t0x = a.x + c.x, t0y = a.y + c.y;
  float t1x = a.x - c.x, t1y = a.y - c.y;
  float t2x = b.x + d.x, t2y = b.y + d.y;
  float t3x = b.x - d.x, t3y = b.y - d.y;
  a = make_float2(t0x + t2x, t0y + t2y);
  c = make_float2(t0x - t2x, t0y - t2y);
  if (SIGN < 0) {
    b = make_float2(t1x + t3y, t1y - t3x);
    d = make_float2(t1x - t3y, t1y + t3x);
  } else {
    b = make_float2(t1x - t3y, t1y + t3x);
    d = make_float2(t1x + t3y, t1y - t3x);
  }
}

// in-register 16-point DFT, natural in / natural out, constant twiddles.
template <int SIGN>
__device__ __forceinline__ void fft16(float2 v[16]) {
  const float sg = (float)SIGN;
  const float C1 = 0.92387953251128674f;
  const float S1 = 0.38268343236508978f;
  const float R2 = 0.70710678118654752f;
  bfly4<SIGN>(v[0], v[4], v[8], v[12]);
  bfly4<SIGN>(v[1], v[5], v[9], v[13]);
  bfly4<SIGN>(v[2], v[6], v[10], v[14]);
  bfly4<SIGN>(v[3], v[7], v[11], v[15]);
  cmul_set(v[5], C1, sg * S1);
  cmul_set(v[6], R2, sg * R2);
  cmul_set(v[7], S1, sg * C1);
  cmul_set(v[9], R2, sg * R2);
  v[10] = make_float2(-sg * v[10].y, sg * v[10].x);
  cmul_set(v[11], -R2, sg * R2);
  cmul_set(v[13], S1, sg * C1);
  cmul_set(v[14], -R2, sg * R2);
  cmul_set(v[15], -C1, -sg * S1);
  float2 w[16];
#pragma unroll
  for (int g = 0; g < 4; ++g) {
    float2 x0 = v[4 * g], x1 = v[4 * g + 1], x2 = v[4 * g + 2],
           x3 = v[4 * g + 3];
    bfly4<SIGN>(x0, x1, x2, x3);
    w[g] = x0; w[g + 4] = x1; w[g + 8] = x2; w[g + 12] = x3;
  }
#pragma unroll
  for (int i = 0; i < 16; ++i) v[i] = w[i];
}

__device__ __forceinline__ void tw_apply(float2 v[16], float ang) {
  float sn, cn;
  __sincosf(ang, &sn, &cn);
  float2 w1 = make_float2(cn, sn), cw = w1;
#pragma unroll
  for (int g = 1; g < 16; ++g) {
    v[g] = cmulf(v[g], cw);
    if (g < 15) cw = cmulf(cw, w1);
  }
}

// ======== pad-17 variant (k_khat only; lds is 4368 float2) ========
// natural -> scrambled. In: v[c] = x[tid+256c].
// Out: v[al] = X[kb + 256*al], kb = (tid>>4) + 16*(tid&15).
template <int SIGN>
__device__ void fft4096_regs(float2 v[16], float2* lds, int tid) {
  const int a = tid & 15, g2 = tid >> 4;
  fft16<SIGN>(v);
  tw_apply(v, (float)SIGN * (2.0f * PI_F / 4096.0f) * (float)tid);
  __syncthreads();
#pragma unroll
  for (int g = 0; g < 16; ++g) lds[tid * 17 + g] = v[g];
  __syncthreads();
#pragma unroll
  for (int b = 0; b < 16; ++b) v[b] = lds[a * 17 + b * 272 + g2];
  fft16<SIGN>(v);
  tw_apply(v, (float)SIGN * (2.0f * PI_F / 256.0f) * (float)a);
  __syncthreads();
#pragma unroll
  for (int b = 0; b < 16; ++b) lds[g2 * 17 + b * 273 + a] = v[b];
  __syncthreads();
#pragma unroll
  for (int a2 = 0; a2 < 16; ++a2) v[a2] = lds[g2 * 17 + a * 273 + a2];
  fft16<SIGN>(v);
  // no trailing barrier; callers must __syncthreads before reusing lds.
}

// ======== swizzled variant (k_conv; lds is exactly 4096 float2) ========
template <int SIGN>
__device__ void fft4096_regs_c(float2 v[16], float2* lds, int tid) {
  const int a = tid & 15, g2 = tid >> 4;
  fft16<SIGN>(v);
  tw_apply(v, (float)SIGN * (2.0f * PI_F / 4096.0f) * (float)tid);
  __syncthreads();
#pragma unroll
  for (int g = 0; g < 16; ++g) lds[(tid << 4) | (g ^ a)] = v[g];
  __syncthreads();
#pragma unroll
  for (int b = 0; b < 16; ++b) v[b] = lds[((a + 16 * b) << 4) | (g2 ^ a)];
  fft16<SIGN>(v);
  tw_apply(v, (float)SIGN * (2.0f * PI_F / 256.0f) * (float)a);
  __syncthreads();
#pragma unroll
  for (int b = 0; b < 16; ++b) lds[(g2 << 8) | (b << 4) | (a ^ b)] = v[b];
  __syncthreads();
#pragma unroll
  for (int a2 = 0; a2 < 16; ++a2) v[a2] = lds[(g2 << 8) | (a << 4) | (a2 ^ a)];
  fft16<SIGN>(v);
  // no trailing barrier.
}

// scrambled -> natural (reverse network), swizzled layout.
template <int SIGN>
__device__ void fft4096_scr2nat_c(float2 v[16], float2* lds, int tid) {
  const int a = tid & 15, g2 = tid >> 4;
  fft16<SIGN>(v);  // over k2
  __syncthreads();  // guard callers' prior lds reads
#pragma unroll
  for (int r = 0; r < 16; ++r) lds[(g2 << 8) | (a << 4) | (r ^ a)] = v[r];
  __syncthreads();
#pragma unroll
  for (int b = 0; b < 16; ++b) v[b] = lds[(g2 << 8) | (b << 4) | (a ^ b)];
  tw_apply(v, (float)SIGN * (2.0f * PI_F / 256.0f) * (float)a);
  fft16<SIGN>(v);  // over k1
  __syncthreads();
#pragma unroll
  for (int r = 0; r < 16; ++r) lds[((16 * r + a) << 4) | (g2 ^ a)] = v[r];
  __syncthreads();
#pragma unroll
  for (int g = 0; g < 16; ++g) v[g] = lds[(tid << 4) | (g ^ a)];
  tw_apply(v, (float)SIGN * (2.0f * PI_F / 4096.0f) * (float)tid);
  fft16<SIGN>(v);  // over k0 -> v[c] = x[tid+256c]
}

// ---------------- Kernel 1a: Cauchy sums -> atRoots ----------------
// 2048 blocks: h=blk>>4, 1 m-point/thread (8 waves/SIMD for latency hiding).
__global__ __launch_bounds__(256) void k_cauchy(
    const float* __restrict__ Lre, const float* __restrict__ Lim,
    const float* __restrict__ Pri, const float* __restrict__ Bri,
    const float* __restrict__ Cri, const float* __restrict__ lstep,
    float2* __restrict__ atR) {
  __shared__ float4 pA[64];
  __shared__ float4 pB[64];
  __shared__ float2 pL[64];
  const int h = blockIdx.x >> 4;
  const int sub = blockIdx.x & 15;
  const int tid = threadIdx.x;
  if (tid < 64) {
    int base = h * 64 + tid;
    float lr = fminf(Lre[base], -1e-4f);
    float li = Lim[base];
    float pr = Pri[2 * base], pi = Pri[2 * base + 1];
    float br = Bri[2 * base], bi = Bri[2 * base + 1];
    float cr = Cri[2 * base], ci = Cri[2 * base + 1];
    pA[tid] = make_float4(cr * br + ci * bi, cr * bi - ci * br,
                          cr * pr + ci * pi, cr * pi - ci * pr);
    pB[tid] = make_float4(pr * br + pi * bi, pr * bi - pi * br,
                          pr * pr + pi * pi, 0.f);
    pL[tid] = make_float2(lr, li);
  }
  __syncthreads();
  const float istep = expf(-lstep[h]);
  const int m = sub * 256 + tid;
  float sn, cn;
  __sincosf(-(2.0f * PI_F / 4096.0f) * (float)m, &sn, &cn);
  const float trm = 0.5f * (1.0f + cn);
  const float tim = 0.5f * sn;
  const float qrm = (1.0f - cn) * istep;
  const float qim = -sn * istep;
  float S0 = 0.f, S1 = 0.f, S2 = 0.f, S3 = 0.f, S4 = 0.f, S5 = 0.f, S6 = 0.f,
        S7 = 0.f;
#pragma unroll 8
  for (int n = 0; n < 64; ++n) {
    float4 a = pA[n];
    float4 b = pB[n];
    float2 L = pL[n];
    float dr = qrm - (trm * L.x - tim * L.y);
    float di = qim - (trm * L.y + tim * L.x);
    float inv = __builtin_amdgcn_rcpf(dr * dr + di * di);
    float sr = dr * inv, si = -di * inv;
    S0 += a.x * sr - a.y * si;  S1 += a.x * si + a.y * sr;
    S2 += a.z * sr - a.w * si;  S3 += a.z * si + a.w * sr;
    S4 += b.x * sr - b.y * si;  S5 += b.x * si + b.y * sr;
    S6 += b.z * sr;             S7 += b.z * si;
  }
  float tS11r = trm * S6 - tim * S7;
  float tS11i = trm * S7 + tim * S6;
  float denr = 1.0f + tS11r, deni = tS11i;
  float dinv = 1.0f / (denr * denr + deni * deni);
  float P1r = S2 * S4 - S3 * S5;
  float P1i = S2 * S5 + S3 * S4;
  float P2r = trm * P1r - tim * P1i;
  float P2i = trm * P1i + tim * P1r;
  float Qr = (P2r * denr + P2i * deni) * dinv;
  float Qi = (P2i * denr - P2r * deni) * dinv;
  atR[h * 4096 + m] = make_float2(S0 - Qr, S1 - Qi);
}

// ---------------- Kernel 1b: atRoots -> alpha/beta table ----------------
__global__ __launch_bounds__(256, 4) void k_khat(
    const float2* __restrict__ atR, const float* __restrict__ Dp,
    float4* __restrict__ abt) {
  __shared__ float2 lds[4368];
  const int h = blockIdx.x;
  const int tid = threadIdx.x;
  float2 v[16];
#pragma unroll
  for (int c = 0; c < 16; ++c) v[c] = atR[h * 4096 + tid + 256 * c];
  fft4096_regs<1>(v, lds, tid);  // unnormalized inverse -> zK (scrambled)
  const int kb = (tid >> 4) + 16 * (tid & 15);
  float* ldsf = (float*)lds;
  const float s = 1.0f / 4096.0f;
  __syncthreads();
#pragma unroll
  for (int al = 0; al < 16; ++al) ldsf[ad(kb + 256 * al)] = v[al].x * s;
  __syncthreads();
  // pack K[2n]+iK[2n+1], zero-pad to 2L
#pragma unroll
  for (int c = 0; c < 8; ++c) {
    int n = tid + 256 * c;
    v[c] = make_float2(ldsf[ad(2 * n)], ldsf[ad(2 * n + 1)]);
  }
#pragma unroll
  for (int c = 8; c < 16; ++c) v[c] = make_float2(0.f, 0.f);
  fft4096_regs<-1>(v, lds, tid);  // forward; scrambled
  __syncthreads();
#pragma unroll
  for (int al = 0; al < 16; ++al) lds[ad(kb + 256 * al)] = v[al];
  __syncthreads();
  const float Dh = Dp[h];
#pragma unroll
  for (int c = 0; c < 16; ++c) {
    int k = kb + 256 * c;
    float2 Zk = lds[ad(k)];
    float2 Zm = lds[ad((4096 - k) & 4095)];
    float Er = 0.5f * (Zk.x + Zm.x), Ei = 0.5f * (Zk.y - Zm.y);
    float Or = 0.5f * (Zk.y + Zm.y), Oi = 0.5f * (Zm.x - Zk.x);
    float s_, c_;
    __sincosf(-(PI_F / 4096.0f) * (float)k, &s_, &c_);
    float Gr = c_ * Or - s_ * Oi, Gi = c_ * Oi + s_ * Or;  // G = W*O
    float ar = (Er + Dh + s_ * Gr) * s;
    float ai = (Ei + s_ * Gi) * s;
    float br = (-c_ * Gi) * s;
    float bi = (c_ * Gr) * s;
    abt[h * 4096 + tid + 256 * c] = make_float4(ar, ai, br, bi);  // scrambled
  }
}

// ---------------- Kernel 2: per-row FFT convolution ----------------
// (256,2): VGPR cap 128 — swizzle variant needs ~77, no spill. LDS (32KB)
// caps occupancy at 5 blocks/CU. See launch_bounds history at top.
__global__ __launch_bounds__(256, 2) void k_conv(const float* __restrict__ u,
                                                 const float4* __restrict__ abt,
                                                 float* __restrict__ y) {
  __shared__ float2 lds[4096];  // exactly 32 KB -> LDS cap 5 blocks/CU
  const int r = blockIdx.x;  // b*128 + h
  const int h = r & 127;
  const int tid = threadIdx.x;
  const float2* u2 = (const float2*)(u + (size_t)r * 4096);
  float2 v[16];
#pragma unroll
  for (int c = 0; c < 8; ++c) v[c] = u2[tid + 256 * c];
#pragma unroll
  for (int c = 8; c < 16; ++c) v[c] = make_float2(0.f, 0.f);
  fft4096_regs_c<-1>(v, lds, tid);  // forward; v[al]=Z[kb+256al]
  const int kb = (tid >> 4) + 16 * (tid & 15);
  __syncthreads();  // lagging T2 reads done before we overwrite
#pragma unroll
  for (int al = 0; al < 16; ++al) lds[sw16(kb + 256 * al)] = v[al];
  __syncthreads();
  const float4* __restrict__ abrow = abt + h * 4096;
#pragma unroll
  for (int al = 0; al < 16; ++al) {
    int k = kb + 256 * al;
    float4 ab = abrow[tid + 256 * al];  // coalesced (pre-scrambled table)
    float2 Zm = lds[sw16((4096 - k) & 4095)];
    float2 Zk = v[al];
    v[al] = make_float2(ab.x * Zk.x - ab.y * Zk.y + ab.z * Zm.x + ab.w * Zm.y,
                        ab.x * Zk.y + ab.y * Zk.x + ab.w * Zm.x - ab.z * Zm.y);
  }
  // inverse from scrambled; internal first sync guards partner reads above
  fft4096_scr2nat_c<1>(v, lds, tid);  // v[c] = ypack[tid+256c]
  float2* y2 = (float2*)(y + (size_t)r * 4096);
#pragma unroll
  for (int c = 0; c < 8; ++c) y2[tid + 256 * c] = v[c];
}

extern "C" void kernel_launch(void* const* d_in, const int* in_sizes, int n_in,
                              void* d_out, int out_size, void* d_ws,
                              size_t ws_size, hipStream_t stream) {
  (void)in_sizes; (void)n_in; (void)out_size; (void)ws_size;
  const float* u = (const float*)d_in[0];
  const float* Lre = (const float*)d_in[1];
  const float* Lim = (const float*)d_in[2];
  const float* Pri = (const float*)d_in[3];
  const float* Bri = (const float*)d_in[4];
  const float* Cri = (const float*)d_in[5];
  const float* lst = (const float*)d_in[6];
  const float* Dp = (const float*)d_in[7];
  float* y = (float*)d_out;
  float2* atR = (float2*)d_ws;                                     // 4 MiB
  float4* abt = (float4*)((char*)d_ws + (size_t)4 * 1024 * 1024);  // 8 MiB

  k_cauchy<<<2048, 256, 0, stream>>>(Lre, Lim, Pri, Bri, Cri, lst, atR);
  k_khat<<<128, 256, 0, stream>>>(atR, Dp, abt);
  k_conv<<<2048, 256, 0, stream>>>(u, abt, y);
}